// Round 7
// baseline (61.577 us; speedup 1.0000x reference)
//
#include <hip/hip_runtime.h>
#include <math.h>

#define N_ 8
#define C_ 256
#define P_ 784
#define K_ 64
#define F_ 16384      // K_*C_
#define FEPS 1e-12f
#define BNEPS 1e-5f
#define PBLK 25       // ceil(784/32)

__device__ __forceinline__ float wave_sum(float v) {
#pragma unroll
  for (int s = 1; s < 64; s <<= 1) v += __shfl_xor(v, s, 64);
  return v;
}
__device__ __forceinline__ float wave_max(float v) {
#pragma unroll
  for (int s = 1; s < 64; s <<= 1) v = fmaxf(v, __shfl_xor(v, s, 64));
  return v;
}

// Fused: per (n, 32-position tile): G[128][32] over full C=256,
// rinv/xn2 inline, cn2, softmax, rn, w2, Spart.
// grid (25, 8), 512 threads. X read straight from global (L1-resident tile),
// A double-buffered in LDS with register prefetch; 1 barrier per chunk.
__global__ __launch_bounds__(512) void k_fused1(const float* __restrict__ x,
                                                const float* __restrict__ convw,
                                                const float* __restrict__ cent,
                                                float* __restrict__ w2,
                                                float* __restrict__ Spart) {
  __shared__ float As[2][128][36];  // [buf][kk][cc] stride 36: b128-aligned
  __shared__ float G_lds[128][34];  // [kk][pp]
  __shared__ float w2_lds[64][36];  // [k][pp]
  __shared__ float cn2p[64][9];
  __shared__ float cn2_lds[64];
  __shared__ float rinv_lds[32];
  __shared__ float xn2_lds[32];
  __shared__ float sp_lds[8][65];

  const int pblk = blockIdx.x, n = blockIdx.y;
  const int p0 = pblk * 32;
  const int t = threadIdx.x;
  const int wv = t >> 6, lane = t & 63;
  const float* xb = x + (size_t)n * C_ * P_;

  const int tx = t & 15, ty = t >> 4;     // tx: p-pair (0..15), ty: kk-quad (0..31)
  const int scc = t & 31, skg = t >> 5;   // staging: col-in-chunk, row-group (0..15)
  const int pbase = p0 + tx * 2;
  const float* xcol = xb + ((pbase + 1 < P_) ? pbase : (P_ - 2));  // clamp tail (values unused)

  // cn2 partials: thread t -> k = t>>3, oct = t&7 (32 floats each)
  {
    int k = t >> 3, oct = t & 7;
    const float* row = cent + (size_t)k * C_ + oct * 32;
    float s = 0.f;
#pragma unroll
    for (int i = 0; i < 8; ++i) {
      float4 v = *(const float4*)&row[i * 4];
      s += v.x * v.x + v.y * v.y + v.z * v.z + v.w * v.w;
    }
    cn2p[k][oct] = s;
  }
  // stage chunk 0 into As[0]
#pragma unroll
  for (int i = 0; i < 8; ++i) {
    int kk = skg * 8 + i;
    const float* Ar = (kk < 64) ? (convw + (size_t)kk * C_) : (cent + (size_t)(kk - 64) * C_);
    As[0][kk][scc] = Ar[scc];
  }
  __syncthreads();
  if (t < 64) {
    float s = 0.f;
#pragma unroll
    for (int i = 0; i < 8; ++i) s += cn2p[t][i];
    cn2_lds[t] = s;
  }

  float acc[4][2] = {};
  float ssq0 = 0.f, ssq1 = 0.f;

  for (int ch = 0; ch < 8; ++ch) {
    const int cur = ch & 1;
    const int c0 = ch * 32;
    // prefetch next A chunk into registers (latency hidden under compute)
    float anext[8];
    if (ch < 7) {
      int c0n = c0 + 32;
#pragma unroll
      for (int i = 0; i < 8; ++i) {
        int kk = skg * 8 + i;
        const float* Ar = (kk < 64) ? (convw + (size_t)kk * C_) : (cent + (size_t)(kk - 64) * C_);
        anext[i] = Ar[c0n + scc];
      }
    }
    // compute: x from global (L1), A from LDS via b128
    const float* xc = xcol + (size_t)c0 * P_;
#pragma unroll
    for (int cc4 = 0; cc4 < 32; cc4 += 4) {
      float2 xv0 = *(const float2*)&xc[(size_t)(cc4 + 0) * P_];
      float2 xv1 = *(const float2*)&xc[(size_t)(cc4 + 1) * P_];
      float2 xv2 = *(const float2*)&xc[(size_t)(cc4 + 2) * P_];
      float2 xv3 = *(const float2*)&xc[(size_t)(cc4 + 3) * P_];
      float4 a0 = *(const float4*)&As[cur][ty * 4 + 0][cc4];
      float4 a1 = *(const float4*)&As[cur][ty * 4 + 1][cc4];
      float4 a2 = *(const float4*)&As[cur][ty * 4 + 2][cc4];
      float4 a3 = *(const float4*)&As[cur][ty * 4 + 3][cc4];
      float xa[4] = {xv0.x, xv1.x, xv2.x, xv3.x};
      float xbv[4] = {xv0.y, xv1.y, xv2.y, xv3.y};
      float av[4][4] = {{a0.x, a0.y, a0.z, a0.w},
                        {a1.x, a1.y, a1.z, a1.w},
                        {a2.x, a2.y, a2.z, a2.w},
                        {a3.x, a3.y, a3.z, a3.w}};
#pragma unroll
      for (int i = 0; i < 4; ++i)
#pragma unroll
        for (int j = 0; j < 4; ++j) {
          acc[i][0] += av[i][j] * xa[j];
          acc[i][1] += av[i][j] * xbv[j];
        }
      if (wv == 0) {  // wave-uniform: only wave 0 owns ssq (threads t<16 used)
#pragma unroll
        for (int j = 0; j < 4; ++j) { ssq0 += xa[j] * xa[j]; ssq1 += xbv[j] * xbv[j]; }
      }
    }
    if (ch < 7) {
      const int nxt = cur ^ 1;
#pragma unroll
      for (int i = 0; i < 8; ++i) As[nxt][skg * 8 + i][scc] = anext[i];
    }
    __syncthreads();
  }

  // G -> LDS; rinv/xn2 from wave-0 registers
#pragma unroll
  for (int i = 0; i < 4; ++i)
    *(float2*)&G_lds[ty * 4 + i][tx * 2] = make_float2(acc[i][0], acc[i][1]);
  if (t < 16) {
    float r0 = 1.0f / fmaxf(sqrtf(ssq0), FEPS);
    float r1 = 1.0f / fmaxf(sqrtf(ssq1), FEPS);
    rinv_lds[tx * 2] = r0;
    rinv_lds[tx * 2 + 1] = r1;
    xn2_lds[tx * 2] = ssq0 * r0 * r0;
    xn2_lds[tx * 2 + 1] = ssq1 * r1 * r1;
  }
  __syncthreads();

  // softmax / rn / w2: wave wv handles pl = wv*4 + j
  float s_acc = 0.f;
  float c2 = cn2_lds[lane];
#pragma unroll
  for (int j = 0; j < 4; ++j) {
    int pl = wv * 4 + j;
    if (p0 + pl < P_) {   // wave-uniform condition
      float r = rinv_lds[pl];
      float x2 = xn2_lds[pl];
      float lg = G_lds[lane][pl] * r;
      float dt = G_lds[64 + lane][pl] * r;
      float m = wave_max(lg);
      float e = expf(lg - m);
      float ssum = wave_sum(e);
      float a = e / ssum;
      float rn2 = wave_sum(a * a * (x2 - 2.f * dt + c2));
      float wf = 1.0f / fmaxf(sqrtf(rn2), FEPS);
      float wval = a * wf;
      s_acc += wval;
      w2_lds[lane][pl] = wval * r;
    }
  }
  sp_lds[wv][lane] = s_acc;
  __syncthreads();
  if (t < 64) {
    float s = 0.f;
#pragma unroll
    for (int g = 0; g < 8; ++g) s += sp_lds[g][t];
    Spart[((size_t)pblk * N_ + n) * 64 + t] = s;
  }
  // w2 global write: thread t: k = t>>3, q = t&7 -> float4 at p0+q*4
  {
    int k = t >> 3, q = t & 7;
    int p = p0 + q * 4;
    if (p + 3 < P_) {
      float4 v = *(const float4*)&w2_lds[k][q * 4];
      *(float4*)&w2[((size_t)n * K_ + k) * P_ + p] = v;
    }
  }
}

// vpart[s][n][k][c] = sum_{p in slice s} w2[n,k,p]*x[n,c,p]
// grid (4 c-tiles, 8 splits, 8 n) = 256 blocks, 4 p-chunks each.
__global__ __launch_bounds__(256) void k_gemm2(const float* __restrict__ x,
                                               const float* __restrict__ w2,
                                               float* __restrict__ vpart) {
  __shared__ float WsT[32][68];   // [pp][k]
  __shared__ float XsT[32][68];   // [pp][c]
  int n = blockIdx.z, s = blockIdx.y;
  int c0 = blockIdx.x * 64;
  int t = threadIdx.x;
  int tx = t & 15, ty = t >> 4;
  float acc[4][4] = {};
  const float* wb = w2 + (size_t)n * K_ * P_;
  const float* xb = x + (size_t)n * C_ * P_;
  int pbase = s * 98;
  for (int q = 0; q < 98; q += 32) {
    int r = t >> 5, pc = t & 31;
    bool ok = (q + pc) < 98;
    int p = pbase + q + pc;
#pragma unroll
    for (int i = 0; i < 8; ++i) {
      int row = r + i * 8;
      WsT[pc][row] = ok ? wb[(size_t)row * P_ + p] : 0.f;
      XsT[pc][row] = ok ? xb[(size_t)(c0 + row) * P_ + p] : 0.f;
    }
    __syncthreads();
#pragma unroll
    for (int pp = 0; pp < 32; ++pp) {
      float4 a = *(const float4*)&WsT[pp][ty * 4];
      float4 bv = *(const float4*)&XsT[pp][tx * 4];
      float av[4] = {a.x, a.y, a.z, a.w};
      float bb[4] = {bv.x, bv.y, bv.z, bv.w};
#pragma unroll
      for (int i = 0; i < 4; ++i)
#pragma unroll
        for (int j = 0; j < 4; ++j) acc[i][j] += av[i] * bb[j];
    }
    __syncthreads();
  }
  float* vb = vpart + (size_t)(s * N_ + n) * K_ * C_;
#pragma unroll
  for (int i = 0; i < 4; ++i)
#pragma unroll
    for (int j = 0; j < 4; ++j)
      vb[(size_t)(ty * 4 + i) * C_ + c0 + tx * 4 + j] = acc[i][j];
}

// vladn[n,k,c] = (sum_s vpart - cent*sum_s Spart) / max(||.||_c, eps). grid 512 (b=n*64+k)
__global__ __launch_bounds__(256) void k_vladnorm(const float* __restrict__ vpart,
                                                  const float* __restrict__ cent,
                                                  const float* __restrict__ Spart,
                                                  float* __restrict__ vladn) {
  __shared__ float red[4];
  int b = blockIdx.x;
  int n = b >> 6, k = b & 63;
  int c = threadIdx.x;
  float Sb = 0.f;
#pragma unroll
  for (int s = 0; s < PBLK; ++s) Sb += Spart[((size_t)s * N_ + n) * 64 + k];
  float val = 0.f;
#pragma unroll
  for (int s = 0; s < 8; ++s) val += vpart[(size_t)(s * 512 + b) * C_ + c];
  val -= cent[(size_t)k * C_ + c] * Sb;
  float ss = wave_sum(val * val);
  int wv = threadIdx.x >> 6, lane = threadIdx.x & 63;
  if (lane == 0) red[wv] = ss;
  __syncthreads();
  float tot = red[0] + red[1] + red[2] + red[3];
  float inv = 1.0f / fmaxf(sqrtf(tot), FEPS);
  vladn[(size_t)b * C_ + c] = val * inv;
}

// BatchNorm over n (biased var) + bn affine; per-block partial ssq into nrmpart.
__global__ __launch_bounds__(256) void k_bn(const float* __restrict__ vladn,
                                            const float* __restrict__ bnw,
                                            const float* __restrict__ bnb,
                                            float* __restrict__ ybuf,
                                            float* __restrict__ nrmpart) {
  __shared__ float red[4][8];
  int f = blockIdx.x * 256 + threadIdx.x;
  float v[N_];
  float s = 0.f;
#pragma unroll
  for (int n = 0; n < N_; ++n) { v[n] = vladn[(size_t)n * F_ + f]; s += v[n]; }
  float mean = s * (1.0f / N_);
  float s2 = 0.f;
#pragma unroll
  for (int n = 0; n < N_; ++n) { float d = v[n] - mean; s2 += d * d; }
  float var = s2 * (1.0f / N_);
  float sc = bnw[f] / sqrtf(var + BNEPS);
  float bb = bnb[f];
  float y[N_];
#pragma unroll
  for (int n = 0; n < N_; ++n) {
    y[n] = (v[n] - mean) * sc + bb;
    ybuf[(size_t)n * F_ + f] = y[n];
  }
  int wv = threadIdx.x >> 6, lane = threadIdx.x & 63;
#pragma unroll
  for (int n = 0; n < N_; ++n) {
    float q = wave_sum(y[n] * y[n]);
    if (lane == 0) red[wv][n] = q;
  }
  __syncthreads();
  if (threadIdx.x < N_) {
    int n = threadIdx.x;
    nrmpart[n * 64 + blockIdx.x] = red[0][n] + red[1][n] + red[2][n] + red[3][n];
  }
}

// out = y / max(||y_n||, eps). grid 512.
__global__ __launch_bounds__(256) void k_final(const float* __restrict__ ybuf,
                                               const float* __restrict__ nrmpart,
                                               float* __restrict__ out) {
  int idx = blockIdx.x * 256 + threadIdx.x;
  int n = idx >> 14;
  float tot = 0.f;
#pragma unroll
  for (int b = 0; b < 64; ++b) tot += nrmpart[n * 64 + b];
  float inv = 1.0f / fmaxf(sqrtf(tot), FEPS);
  out[idx] = ybuf[idx] * inv;
}

extern "C" void kernel_launch(void* const* d_in, const int* in_sizes, int n_in,
                              void* d_out, int out_size, void* d_ws, size_t ws_size,
                              hipStream_t stream) {
  const float* x = (const float*)d_in[0];
  const float* convw = (const float*)d_in[1];
  const float* cent = (const float*)d_in[2];
  const float* bnw = (const float*)d_in[3];
  const float* bnb = (const float*)d_in[4];
  float* out = (float*)d_out;
  float* ws = (float*)d_ws;

  float* Spart = ws;                // 25*8*64 = 12800
  float* nrmpart = ws + 12800;      // 512
  float* w2 = ws + 13312;           // 8*64*784 = 401408
  float* vpart = ws + 414720;       // 8*512*256 = 1048576
  float* vladn = ws + 1463296;      // 131072
  float* ybuf = ws + 1594368;       // 131072  (end: 1725440 floats ~6.9MB)

  k_fused1<<<dim3(PBLK, N_), 512, 0, stream>>>(x, convw, cent, w2, Spart);
  k_gemm2<<<dim3(4, 8, 8), 256, 0, stream>>>(x, w2, vpart);
  k_vladnorm<<<512, 256, 0, stream>>>(vpart, cent, Spart, vladn);
  k_bn<<<64, 256, 0, stream>>>(vladn, bnw, bnb, ybuf, nrmpart);
  k_final<<<512, 256, 0, stream>>>(ybuf, nrmpart, out);
}

// Round 8
// 59.025 us; speedup vs baseline: 1.0432x; 1.0432x over previous
//
#include <hip/hip_runtime.h>
#include <math.h>

#define N_ 8
#define C_ 256
#define P_ 784
#define K_ 64
#define F_ 16384      // K_*C_
#define FEPS 1e-12f
#define BNEPS 1e-5f
#define PBLK 25       // ceil(784/32)

__device__ __forceinline__ float wave_sum(float v) {
#pragma unroll
  for (int s = 1; s < 64; s <<= 1) v += __shfl_xor(v, s, 64);
  return v;
}
__device__ __forceinline__ float wave_max(float v) {
#pragma unroll
  for (int s = 1; s < 64; s <<= 1) v = fmaxf(v, __shfl_xor(v, s, 64));
  return v;
}

// Fused: per (n, 32-position tile): G[128][32] over full C=256,
// rinv/xn2 inline, cn2, softmax, rn, w2, Spart.  grid (25,8), 512 threads.
// Thread-halves split each 32-c chunk (grp0: cc 0-15, grp1: cc 16-31);
// per-thread 4kk x 4p; x loads fully coalesced (8 consecutive floats/instr);
// A in LDS transposed [cc][kk], ds_read_b128, single buffer + reg prefetch.
__global__ __launch_bounds__(512) void k_fused1(const float* __restrict__ x,
                                                const float* __restrict__ convw,
                                                const float* __restrict__ cent,
                                                float* __restrict__ w2,
                                                float* __restrict__ Spart) {
  __shared__ float AsT[32][136];    // [cc][kk] rows 544B (16B-aligned)
  __shared__ float G_lds[128][34];  // [kk][pp]
  __shared__ float ubuf[64 * 36];   // w2_lds[64][36]; cn2p[64][9] overlaid
  __shared__ float cn2_lds[64];
  __shared__ float ssq_ab[2][32];
  __shared__ float rinv_lds[32];
  __shared__ float xn2_lds[32];
  __shared__ float sp_lds[8][65];

  float (*w2_lds)[36] = (float(*)[36])ubuf;
  float (*cn2p)[9] = (float(*)[9])ubuf;

  const int pblk = blockIdx.x, n = blockIdx.y;
  const int p0 = pblk * 32;
  const int t = threadIdx.x;
  const int wv = t >> 6, lane = t & 63;
  const int grp = t >> 8;           // cc-half owner
  const int tl = t & 255;
  const int ty = tl >> 3;           // 0..31 -> kk rows ty*4..ty*4+3
  const int tx = tl & 7;            // 0..7  -> p cols {tx, tx+8, tx+16, tx+24}
  const int ccb = grp * 16;
  const float* xb = x + (size_t)n * C_ * P_;

  int pj[4];
#pragma unroll
  for (int j = 0; j < 4; ++j) {
    int p = p0 + tx + 8 * j;
    pj[j] = (p < P_) ? p : 0;       // clamp tail; junk values never used
  }

  // cn2 partials: thread t -> k = t>>3, oct = t&7 (32 floats each)
  {
    int k = t >> 3, oct = t & 7;
    const float* row = cent + (size_t)k * C_ + oct * 32;
    float s = 0.f;
#pragma unroll
    for (int i = 0; i < 8; ++i) {
      float4 v = *(const float4*)&row[i * 4];
      s += v.x * v.x + v.y * v.y + v.z * v.z + v.w * v.w;
    }
    cn2p[k][oct] = s;
  }
  // stage chunk 0: scc = t&31 (cc), sk = t>>5 (0..15) -> kk = sk*8+i (coalesced reads)
  const int scc = t & 31, sk = t >> 5;
#pragma unroll
  for (int i = 0; i < 8; ++i) {
    int kk = sk * 8 + i;
    const float* Ar = (kk < 64) ? (convw + (size_t)kk * C_) : (cent + (size_t)(kk - 64) * C_);
    AsT[scc][kk] = Ar[scc];
  }
  __syncthreads();

  float acc[4][4] = {};
  float ssqr[4] = {0.f, 0.f, 0.f, 0.f};

  for (int ch = 0; ch < 8; ++ch) {
    const int c0 = ch * 32;
    float anext[8];
    if (ch < 7) {
      int c0n = c0 + 32;
#pragma unroll
      for (int i = 0; i < 8; ++i) {
        int kk = sk * 8 + i;
        const float* Ar = (kk < 64) ? (convw + (size_t)kk * C_) : (cent + (size_t)(kk - 64) * C_);
        anext[i] = Ar[c0n + scc];
      }
    }
    if (ch == 0 && t < 64) {  // fold cn2 once (cn2p lives in ubuf, read before w2 writes)
      float s = 0.f;
#pragma unroll
      for (int i = 0; i < 8; ++i) s += cn2p[t][i];
      cn2_lds[t] = s;
    }
    // compute this group's 16 cc of the chunk
#pragma unroll
    for (int cc = 0; cc < 16; ++cc) {
      const float* xr = xb + (size_t)(c0 + ccb + cc) * P_;
      float xv[4];
#pragma unroll
      for (int j = 0; j < 4; ++j) xv[j] = xr[pj[j]];   // 1-line wave loads
      float4 a = *(const float4*)&AsT[ccb + cc][ty * 4];
      if (ty == 0) {
#pragma unroll
        for (int j = 0; j < 4; ++j) ssqr[j] += xv[j] * xv[j];
      }
      float av[4] = {a.x, a.y, a.z, a.w};
#pragma unroll
      for (int i = 0; i < 4; ++i)
#pragma unroll
        for (int j = 0; j < 4; ++j) acc[i][j] += av[i] * xv[j];
    }
    __syncthreads();
    if (ch < 7) {
#pragma unroll
      for (int i = 0; i < 8; ++i) AsT[scc][sk * 8 + i] = anext[i];
      __syncthreads();
    }
  }

  // Phase A: grp0 writes G; both groups write ssq partials
  if (grp == 0) {
#pragma unroll
    for (int i = 0; i < 4; ++i)
#pragma unroll
      for (int j = 0; j < 4; ++j) G_lds[ty * 4 + i][tx + 8 * j] = acc[i][j];
  }
  if (ty == 0) {
#pragma unroll
    for (int j = 0; j < 4; ++j) ssq_ab[grp][tx + 8 * j] = ssqr[j];
  }
  __syncthreads();
  // Phase B: grp1 accumulates its cc-half
  if (grp == 1) {
#pragma unroll
    for (int i = 0; i < 4; ++i)
#pragma unroll
      for (int j = 0; j < 4; ++j) G_lds[ty * 4 + i][tx + 8 * j] += acc[i][j];
  }
  __syncthreads();
  if (t < 32) {
    float s = ssq_ab[0][t] + ssq_ab[1][t];
    float r = 1.0f / fmaxf(sqrtf(s), FEPS);
    rinv_lds[t] = r;
    xn2_lds[t] = s * r * r;
  }
  __syncthreads();

  // softmax / rn / w2: wave wv handles pl = wv*4 + j
  float s_acc = 0.f;
  float c2 = cn2_lds[lane];
#pragma unroll
  for (int j = 0; j < 4; ++j) {
    int pl = wv * 4 + j;
    if (p0 + pl < P_) {   // wave-uniform condition
      float r = rinv_lds[pl];
      float x2 = xn2_lds[pl];
      float lg = G_lds[lane][pl] * r;
      float dt = G_lds[64 + lane][pl] * r;
      float m = wave_max(lg);
      float e = expf(lg - m);
      float ssum = wave_sum(e);
      float a = e / ssum;
      float rn2 = wave_sum(a * a * (x2 - 2.f * dt + c2));
      float wf = 1.0f / fmaxf(sqrtf(rn2), FEPS);
      float wval = a * wf;
      s_acc += wval;
      w2_lds[lane][pl] = wval * r;
    }
  }
  sp_lds[wv][lane] = s_acc;
  __syncthreads();
  if (t < 64) {
    float s = 0.f;
#pragma unroll
    for (int g = 0; g < 8; ++g) s += sp_lds[g][t];
    Spart[((size_t)pblk * N_ + n) * 64 + t] = s;
  }
  // w2 global write: thread t: k = t>>3, q = t&7 -> float4 at p0+q*4
  {
    int k = t >> 3, q = t & 7;
    int p = p0 + q * 4;
    if (p + 3 < P_) {
      float4 v = *(const float4*)&w2_lds[k][q * 4];
      *(float4*)&w2[((size_t)n * K_ + k) * P_ + p] = v;
    }
  }
}

// vpart[s][n][k][c] = sum_{p in slice s} w2[n,k,p]*x[n,c,p]
// grid (4 c-tiles, 8 splits, 8 n) = 256 blocks, 4 p-chunks each.
__global__ __launch_bounds__(256) void k_gemm2(const float* __restrict__ x,
                                               const float* __restrict__ w2,
                                               float* __restrict__ vpart) {
  __shared__ float WsT[32][68];   // [pp][k]
  __shared__ float XsT[32][68];   // [pp][c]
  int n = blockIdx.z, s = blockIdx.y;
  int c0 = blockIdx.x * 64;
  int t = threadIdx.x;
  int tx = t & 15, ty = t >> 4;
  float acc[4][4] = {};
  const float* wb = w2 + (size_t)n * K_ * P_;
  const float* xb = x + (size_t)n * C_ * P_;
  int pbase = s * 98;
  for (int q = 0; q < 98; q += 32) {
    int r = t >> 5, pc = t & 31;
    bool ok = (q + pc) < 98;
    int p = pbase + q + pc;
#pragma unroll
    for (int i = 0; i < 8; ++i) {
      int row = r + i * 8;
      WsT[pc][row] = ok ? wb[(size_t)row * P_ + p] : 0.f;
      XsT[pc][row] = ok ? xb[(size_t)(c0 + row) * P_ + p] : 0.f;
    }
    __syncthreads();
#pragma unroll
    for (int pp = 0; pp < 32; ++pp) {
      float4 a = *(const float4*)&WsT[pp][ty * 4];
      float4 bv = *(const float4*)&XsT[pp][tx * 4];
      float av[4] = {a.x, a.y, a.z, a.w};
      float bb[4] = {bv.x, bv.y, bv.z, bv.w};
#pragma unroll
      for (int i = 0; i < 4; ++i)
#pragma unroll
        for (int j = 0; j < 4; ++j) acc[i][j] += av[i] * bb[j];
    }
    __syncthreads();
  }
  float* vb = vpart + (size_t)(s * N_ + n) * K_ * C_;
#pragma unroll
  for (int i = 0; i < 4; ++i)
#pragma unroll
    for (int j = 0; j < 4; ++j)
      vb[(size_t)(ty * 4 + i) * C_ + c0 + tx * 4 + j] = acc[i][j];
}

// vladn[n,k,c] = (sum_s vpart - cent*sum_s Spart) / max(||.||_c, eps). grid 512 (b=n*64+k)
__global__ __launch_bounds__(256) void k_vladnorm(const float* __restrict__ vpart,
                                                  const float* __restrict__ cent,
                                                  const float* __restrict__ Spart,
                                                  float* __restrict__ vladn) {
  __shared__ float red[4];
  int b = blockIdx.x;
  int n = b >> 6, k = b & 63;
  int c = threadIdx.x;
  float Sb = 0.f;
#pragma unroll
  for (int s = 0; s < PBLK; ++s) Sb += Spart[((size_t)s * N_ + n) * 64 + k];
  float val = 0.f;
#pragma unroll
  for (int s = 0; s < 8; ++s) val += vpart[(size_t)(s * 512 + b) * C_ + c];
  val -= cent[(size_t)k * C_ + c] * Sb;
  float ss = wave_sum(val * val);
  int wv = threadIdx.x >> 6, lane = threadIdx.x & 63;
  if (lane == 0) red[wv] = ss;
  __syncthreads();
  float tot = red[0] + red[1] + red[2] + red[3];
  float inv = 1.0f / fmaxf(sqrtf(tot), FEPS);
  vladn[(size_t)b * C_ + c] = val * inv;
}

// BatchNorm over n (biased var) + bn affine; per-block partial ssq into nrmpart.
__global__ __launch_bounds__(256) void k_bn(const float* __restrict__ vladn,
                                            const float* __restrict__ bnw,
                                            const float* __restrict__ bnb,
                                            float* __restrict__ ybuf,
                                            float* __restrict__ nrmpart) {
  __shared__ float red[4][8];
  int f = blockIdx.x * 256 + threadIdx.x;
  float v[N_];
  float s = 0.f;
#pragma unroll
  for (int n = 0; n < N_; ++n) { v[n] = vladn[(size_t)n * F_ + f]; s += v[n]; }
  float mean = s * (1.0f / N_);
  float s2 = 0.f;
#pragma unroll
  for (int n = 0; n < N_; ++n) { float d = v[n] - mean; s2 += d * d; }
  float var = s2 * (1.0f / N_);
  float sc = bnw[f] / sqrtf(var + BNEPS);
  float bb = bnb[f];
  float y[N_];
#pragma unroll
  for (int n = 0; n < N_; ++n) {
    y[n] = (v[n] - mean) * sc + bb;
    ybuf[(size_t)n * F_ + f] = y[n];
  }
  int wv = threadIdx.x >> 6, lane = threadIdx.x & 63;
#pragma unroll
  for (int n = 0; n < N_; ++n) {
    float q = wave_sum(y[n] * y[n]);
    if (lane == 0) red[wv][n] = q;
  }
  __syncthreads();
  if (threadIdx.x < N_) {
    int n = threadIdx.x;
    nrmpart[n * 64 + blockIdx.x] = red[0][n] + red[1][n] + red[2][n] + red[3][n];
  }
}

// out = y / max(||y_n||, eps). grid 512.
__global__ __launch_bounds__(256) void k_final(const float* __restrict__ ybuf,
                                               const float* __restrict__ nrmpart,
                                               float* __restrict__ out) {
  int idx = blockIdx.x * 256 + threadIdx.x;
  int n = idx >> 14;
  float tot = 0.f;
#pragma unroll
  for (int b = 0; b < 64; ++b) tot += nrmpart[n * 64 + b];
  float inv = 1.0f / fmaxf(sqrtf(tot), FEPS);
  out[idx] = ybuf[idx] * inv;
}

extern "C" void kernel_launch(void* const* d_in, const int* in_sizes, int n_in,
                              void* d_out, int out_size, void* d_ws, size_t ws_size,
                              hipStream_t stream) {
  const float* x = (const float*)d_in[0];
  const float* convw = (const float*)d_in[1];
  const float* cent = (const float*)d_in[2];
  const float* bnw = (const float*)d_in[3];
  const float* bnb = (const float*)d_in[4];
  float* out = (float*)d_out;
  float* ws = (float*)d_ws;

  float* Spart = ws;                // 25*8*64 = 12800
  float* nrmpart = ws + 12800;      // 512
  float* w2 = ws + 13312;           // 8*64*784 = 401408
  float* vpart = ws + 414720;       // 8*512*256 = 1048576
  float* vladn = ws + 1463296;      // 131072
  float* ybuf = ws + 1594368;       // 131072  (end: 1725440 floats ~6.9MB)

  k_fused1<<<dim3(PBLK, N_), 512, 0, stream>>>(x, convw, cent, w2, Spart);
  k_gemm2<<<dim3(4, 8, 8), 256, 0, stream>>>(x, w2, vpart);
  k_vladnorm<<<512, 256, 0, stream>>>(vpart, cent, Spart, vladn);
  k_bn<<<64, 256, 0, stream>>>(vladn, bnw, bnb, ybuf, nrmpart);
  k_final<<<512, 256, 0, stream>>>(ybuf, nrmpart, out);
}